// Round 5
// baseline (864.471 us; speedup 1.0000x reference)
//
#include <hip/hip_runtime.h>
#include <math.h>

#define NN 50000
#define EN 200000
#define CC 4
#define HH 128
#define GG 64
#define LDSA 136  // padded stride for pool-variant tile
#define LDSF 132  // f32 stride for fused-pool tile

typedef __attribute__((ext_vector_type(8))) short bs8;
typedef __attribute__((ext_vector_type(4))) float f32x4;
typedef __attribute__((ext_vector_type(2))) float f32x2;

__device__ __forceinline__ unsigned short f2bf(float f) {
  unsigned int u = __float_as_uint(f);
  u += 0x7FFFu + ((u >> 16) & 1u);
  return (unsigned short)(u >> 16);
}
__device__ __forceinline__ float bf2f(unsigned short h) {
  return __uint_as_float(((unsigned int)h) << 16);
}
// split 8 f32 into hi/lo bf16 fragments (exactly the ops the old LDS stage did)
__device__ __forceinline__ void cvt_hi_lo(const f32x4& v0, const f32x4& v1, bs8& h, bs8& l) {
  h[0] = f2bf(v0[0]); h[1] = f2bf(v0[1]); h[2] = f2bf(v0[2]); h[3] = f2bf(v0[3]);
  h[4] = f2bf(v1[0]); h[5] = f2bf(v1[1]); h[6] = f2bf(v1[2]); h[7] = f2bf(v1[3]);
  l[0] = f2bf(v0[0] - bf2f(h[0])); l[1] = f2bf(v0[1] - bf2f(h[1]));
  l[2] = f2bf(v0[2] - bf2f(h[2])); l[3] = f2bf(v0[3] - bf2f(h[3]));
  l[4] = f2bf(v1[0] - bf2f(h[4])); l[5] = f2bf(v1[1] - bf2f(h[5]));
  l[6] = f2bf(v1[2] - bf2f(h[6])); l[7] = f2bf(v1[3] - bf2f(h[7]));
}
// fast erf-GELU: A&S 7.1.26 minimax (|erf err| ~1.5e-7) + hw rcp/exp
__device__ __forceinline__ float gelu_f(float x) {
  float z = fabsf(x) * 0.7071067811865476f;
  float t = __builtin_amdgcn_rcpf(fmaf(0.3275911f, z, 1.0f));
  float poly = t * fmaf(t, fmaf(t, fmaf(t, fmaf(t, 1.061405429f, -1.453152027f),
                                        1.421413741f), -0.284496736f), 0.254829592f);
  float e = fmaf(-poly, __expf(-z * z), 1.0f);
  return 0.5f * x * (1.0f + copysignf(e, x));
}
// 2*gelu(x) = x*(1+erf(x/sqrt2)) — caller pre-folds the 0.5 into the edge mask
__device__ __forceinline__ float gelu2_f(float x) {
  float z = fabsf(x) * 0.7071067811865476f;
  float t = __builtin_amdgcn_rcpf(fmaf(0.3275911f, z, 1.0f));
  float poly = t * fmaf(t, fmaf(t, fmaf(t, fmaf(t, 1.061405429f, -1.453152027f),
                                        1.421413741f), -0.284496736f), 0.254829592f);
  float e = fmaf(-poly, __expf(-z * z), 1.0f);
  return x * (1.0f + copysignf(e, x));
}

// ---------------- CSR build ----------------
__global__ __launch_bounds__(256) void count_kernel(const int* __restrict__ dst,
                                                    int* __restrict__ counts) {
  int e = blockIdx.x * 256 + threadIdx.x;
  if (e < EN) atomicAdd(&counts[dst[e]], 1);
}

__global__ __launch_bounds__(256) void block_sum_kernel(const int* __restrict__ counts,
                                                        int* __restrict__ bsums) {
  int tid = threadIdx.x;
  int i = blockIdx.x * 256 + tid;
  int v = (i < NN) ? counts[i] : 0;
#pragma unroll
  for (int d = 1; d < 64; d <<= 1) v += __shfl_xor(v, d);
  __shared__ int ws4[4];
  if ((tid & 63) == 0) ws4[tid >> 6] = v;
  __syncthreads();
  if (tid == 0) bsums[blockIdx.x] = ws4[0] + ws4[1] + ws4[2] + ws4[3];
}

__global__ __launch_bounds__(256) void bsum_scan_kernel(const int* __restrict__ bsums,
                                                        int* __restrict__ boffs, int nb) {
  int tid = threadIdx.x, lane = tid & 63, wv = tid >> 6;
  int v = (tid < nb) ? bsums[tid] : 0;
  int s = v;
#pragma unroll
  for (int d = 1; d < 64; d <<= 1) { int t = __shfl_up(s, d); if (lane >= d) s += t; }
  __shared__ int wsum[4];
  if (lane == 63) wsum[wv] = s;
  __syncthreads();
  int pre = 0;
  for (int j = 0; j < wv; ++j) pre += wsum[j];
  if (tid < nb) boffs[tid] = pre + s - v;
}

__global__ __launch_bounds__(256) void block_scan_kernel(const int* __restrict__ counts,
                                                         const int* __restrict__ boffs,
                                                         int* __restrict__ offsets,
                                                         int* __restrict__ cursor) {
  int tid = threadIdx.x, lane = tid & 63, wv = tid >> 6;
  int i = blockIdx.x * 256 + tid;
  int v = (i < NN) ? counts[i] : 0;
  int s = v;
#pragma unroll
  for (int d = 1; d < 64; d <<= 1) { int t = __shfl_up(s, d); if (lane >= d) s += t; }
  __shared__ int wsum[4];
  if (lane == 63) wsum[wv] = s;
  __syncthreads();
  int pre = boffs[blockIdx.x];
  for (int j = 0; j < wv; ++j) pre += wsum[j];
  if (i < NN) { int e = pre + s - v; offsets[i] = e; cursor[i] = e; }
  if (i == 0) offsets[NN] = EN;
}

// fill: build CSR-ordered side arrays so agg has NO dependent random index chain
// and NO line-wasting random 4B emask reads:
//   csr_es[pos]  = (edge id, src node)   — one 8B load gives both
//   emask_s[pos] = emask[0..3][e]        — one sequential 16B load per edge
__global__ __launch_bounds__(256) void fill_kernel(const int* __restrict__ dst,
                                                   const int* __restrict__ src,
                                                   const float* __restrict__ emask,
                                                   int* __restrict__ cursor,
                                                   int2* __restrict__ csr_es,
                                                   float4* __restrict__ emask_s) {
  int e = blockIdx.x * 256 + threadIdx.x;
  if (e < EN) {
    int s = src[e];
    float m0 = emask[e];
    float m1 = emask[EN + e];
    float m2 = emask[2 * EN + e];
    float m3 = emask[3 * EN + e];
    int pos = atomicAdd(&cursor[dst[e]], 1);
    csr_es[pos] = make_int2(e, s);
    emask_s[pos] = make_float4(m0, m1, m2, m3);
  }
}

// ---------------- weight prep: transpose + hi/lo bf16 split (all 6 matrices) ------
__global__ __launch_bounds__(256) void prep_w_kernel(const float* __restrict__ W1,
                                                     const float* __restrict__ W2,
                                                     const float* __restrict__ Wm1,
                                                     const float* __restrict__ Wm2,
                                                     unsigned short* __restrict__ wts) {
  int m = blockIdx.x >> 6;
  int idx = (blockIdx.x & 63) * 256 + threadIdx.x;  // 0..16383
  const float* src = (m == 0) ? W1 : (m == 1) ? W1 + 16384 : (m == 2) ? W2
                     : (m == 3) ? W2 + 16384 : (m == 4) ? Wm1 : Wm2;
  unsigned short* dhi = wts + m * 32768;
  unsigned short* dlo = dhi + 16384;
  int n = idx >> 7, k = idx & 127;
  float v = src[k * HH + n];  // src [k][n] -> dst [n][k]
  unsigned short hi = f2bf(v);
  dhi[n * HH + k] = hi;
  dlo[n * HH + k] = f2bf(v - bf2f(hi));
}

// ---------------- bond encoder: 16 edges per block ----------------
__global__ __launch_bounds__(256) void ee_kernel(const float* __restrict__ eattr,
                                                 const float* __restrict__ Wbe,
                                                 const float* __restrict__ bbe,
                                                 float* __restrict__ ee) {
  __shared__ float Ws[16 * HH];
  __shared__ float Ea[16 * 16];
  int tid = threadIdx.x;
  int e0 = blockIdx.x * 16;
#pragma unroll
  for (int i = 0; i < 8; ++i) Ws[tid + i * 256] = Wbe[tid + i * 256];
  Ea[tid] = eattr[(size_t)e0 * 16 + tid];
  __syncthreads();
  int h = tid & 127, half = tid >> 7;
  float bb = bbe[h];
#pragma unroll
  for (int j = 0; j < 8; ++j) {
    int el = j * 2 + half;
    float acc = bb;
#pragma unroll
    for (int d = 0; d < 16; ++d) acc += Ea[el * 16 + d] * Ws[d * HH + h];
    ee[(size_t)(e0 + el) * HH + h] = acc;
  }
}

// ---- message aggregation: one wave per node, one edge per wave (float2/lane).
// Depth-2 software pipeline on edge data. Per edge: one sequential int2 (e,src),
// one sequential float4 emask, 512B ee, 4x512B x-gather. hout is nt-stored so the
// streaming output never evicts x/ee from the 256MB L3 (x+ee = 204.8MB fits).
__global__ __launch_bounds__(256) void agg_kernel(const float* __restrict__ x,
                                                  const float* __restrict__ ee,
                                                  const int* __restrict__ off,
                                                  const int2* __restrict__ csr_es,
                                                  const float4* __restrict__ emask_s,
                                                  const float* __restrict__ epsp, int layer,
                                                  float* __restrict__ hout) {
  int wv = threadIdx.x >> 6, lane = threadIdx.x & 63;
  int v = blockIdx.x * 4 + wv;
  int c2 = lane * 2;
  float2 acc[CC];
#pragma unroll
  for (int c = 0; c < CC; ++c) { acc[c].x = 0.f; acc[c].y = 0.f; }
  int beg = off[v], end = off[v + 1];

  // pipeline state: data for edge t (current), index pair for edge t+1
  float2 eeC; float2 xC[CC]; float emC[CC];
  int2 esN = make_int2(0, 0);
  eeC.x = 0.f; eeC.y = 0.f;
#pragma unroll
  for (int c = 0; c < CC; ++c) { xC[c].x = 0.f; xC[c].y = 0.f; emC[c] = 0.f; }

  if (beg < end) {
    int2 es0 = csr_es[beg];
    eeC = *(const float2*)(ee + (size_t)es0.x * HH + c2);
#pragma unroll
    for (int c = 0; c < CC; ++c)
      xC[c] = *(const float2*)(x + ((size_t)c * NN + es0.y) * HH + c2);
    float4 m = emask_s[beg];
    emC[0] = 0.5f * m.x; emC[1] = 0.5f * m.y; emC[2] = 0.5f * m.z; emC[3] = 0.5f * m.w;
    if (beg + 1 < end) esN = csr_es[beg + 1];
  }

  for (int t = beg; t < end; ++t) {
    // issue loads for edge t+1 (data) and t+2 (index pair) before touching eeC/xC
    float2 eeB; float2 xB[CC]; float emB[CC];
    int2 esNN = make_int2(0, 0);
    if (t + 1 < end) {
      eeB = *(const float2*)(ee + (size_t)esN.x * HH + c2);
#pragma unroll
      for (int c = 0; c < CC; ++c)
        xB[c] = *(const float2*)(x + ((size_t)c * NN + esN.y) * HH + c2);
      float4 m = emask_s[t + 1];
      emB[0] = 0.5f * m.x; emB[1] = 0.5f * m.y; emB[2] = 0.5f * m.z; emB[3] = 0.5f * m.w;
      if (t + 2 < end) esNN = csr_es[t + 2];
    } else {
      eeB.x = 0.f; eeB.y = 0.f;
#pragma unroll
      for (int c = 0; c < CC; ++c) { xB[c].x = 0.f; xB[c].y = 0.f; emB[c] = 0.f; }
    }
    // compute edge t (em already carries the 0.5 of gelu)
#pragma unroll
    for (int c = 0; c < CC; ++c) {
      acc[c].x += gelu2_f(xC[c].x + eeC.x) * emC[c];
      acc[c].y += gelu2_f(xC[c].y + eeC.y) * emC[c];
    }
    // rotate pipeline registers
    eeC = eeB;
#pragma unroll
    for (int c = 0; c < CC; ++c) { xC[c] = xB[c]; emC[c] = emB[c]; }
    esN = esNN;
  }

  float ep = 1.0f + epsp[layer];
#pragma unroll
  for (int c = 0; c < CC; ++c) {
    float2 xs = *(const float2*)(x + ((size_t)c * NN + v) * HH + c2);
    f32x2 o;
    o[0] = fmaf(ep, xs.x, acc[c].x);
    o[1] = fmaf(ep, xs.y, acc[c].y);
    __builtin_nontemporal_store(o, (f32x2*)(hout + ((size_t)c * NN + v) * HH + c2));
  }
}

// ---------------- MLP (mode-0), 64 rows/block ------------------------------------
// GEMM1 A-fragments load DIRECTLY from global f32 (no transpose exists: memory is
// [row][k] and the MFMA A-frag is [row][k]) and convert to hi/lo bf16 in registers.
// This deletes the LDS stage phase and two of the three barriers; LDS (32 KB,
// XOR-swizzled) only carries the GEMM1->GEMM2 intermediate t. B-frags are loaded
// per-ks inside the unrolled loops (VGPR=68 proved "preload arrays" never fit).
__global__ __launch_bounds__(256, 4) void mlp_kernel(
    const float* __restrict__ in,
    const unsigned short* __restrict__ w1hi, const unsigned short* __restrict__ w1lo,
    const float* __restrict__ b1,
    const unsigned short* __restrict__ w2hi, const unsigned short* __restrict__ w2lo,
    const float* __restrict__ b2,
    float* __restrict__ out) {
  __shared__ __align__(16) unsigned short AB[2 * 64 * HH];  // t hi plane, lo plane
  unsigned short* Ahi = AB;
  unsigned short* Alo = AB + 64 * HH;
  int tid = threadIdx.x;
  int row0 = blockIdx.x * 64;
  int lane = tid & 63, wq = tid >> 6;
  int ln = lane & 15, quad = lane >> 4;

  f32x4 acc[4][2];
#pragma unroll
  for (int mt = 0; mt < 4; ++mt)
#pragma unroll
    for (int nt = 0; nt < 2; ++nt)
#pragma unroll
      for (int r = 0; r < 4; ++r) acc[mt][nt][r] = 0.f;

  // GEMM1 (3-term split), A direct from global
#pragma unroll
  for (int ks = 0; ks < 4; ++ks) {
    bs8 bh[2], bl[2];
#pragma unroll
    for (int nt = 0; nt < 2; ++nt) {
      int wrow = ((wq * 2 + nt) * 16 + ln) * HH + ks * 32 + quad * 8;
      bh[nt] = *(const bs8*)(w1hi + wrow);
      bl[nt] = *(const bs8*)(w1lo + wrow);
    }
#pragma unroll
    for (int mt = 0; mt < 4; ++mt) {
      const float* p = in + (size_t)(row0 + mt * 16 + ln) * HH + ks * 32 + quad * 8;
      f32x4 v0 = __builtin_nontemporal_load((const f32x4*)p);
      f32x4 v1 = __builtin_nontemporal_load((const f32x4*)(p + 4));
      bs8 ah, al;
      cvt_hi_lo(v0, v1, ah, al);
#pragma unroll
      for (int nt = 0; nt < 2; ++nt) {
        acc[mt][nt] = __builtin_amdgcn_mfma_f32_16x16x32_bf16(al, bh[nt], acc[mt][nt], 0, 0, 0);
        acc[mt][nt] = __builtin_amdgcn_mfma_f32_16x16x32_bf16(ah, bl[nt], acc[mt][nt], 0, 0, 0);
        acc[mt][nt] = __builtin_amdgcn_mfma_f32_16x16x32_bf16(ah, bh[nt], acc[mt][nt], 0, 0, 0);
      }
    }
  }

  // t = gelu(acc + b1) -> swizzled LDS hi/lo (first and only LDS use before barrier)
#pragma unroll
  for (int nt = 0; nt < 2; ++nt) {
    int col = (wq * 2 + nt) * 16 + ln;
    int cb = col >> 3, co = col & 7;
    float bb = b1[col];
#pragma unroll
    for (int mt = 0; mt < 4; ++mt)
#pragma unroll
      for (int r = 0; r < 4; ++r) {
        float tv = gelu_f(acc[mt][nt][r] + bb);
        unsigned short th = f2bf(tv);
        int rr = mt * 16 + quad * 4 + r;
        int sof = rr * HH + (cb ^ (rr & 15)) * 8 + co;
        Ahi[sof] = th;
        Alo[sof] = f2bf(tv - bf2f(th));
      }
  }
  __syncthreads();  // t staged

#pragma unroll
  for (int mt = 0; mt < 4; ++mt)
#pragma unroll
    for (int nt = 0; nt < 2; ++nt)
#pragma unroll
      for (int r = 0; r < 4; ++r) acc[mt][nt][r] = 0.f;
  // GEMM2
#pragma unroll
  for (int ks = 0; ks < 4; ++ks) {
    bs8 bh[2], bl[2];
#pragma unroll
    for (int nt = 0; nt < 2; ++nt) {
      int wrow = ((wq * 2 + nt) * 16 + ln) * HH + ks * 32 + quad * 8;
      bh[nt] = *(const bs8*)(w2hi + wrow);
      bl[nt] = *(const bs8*)(w2lo + wrow);
    }
    bs8 ah[4], al[4];
    int sb = ((ks * 4 + quad) ^ ln) * 8;
#pragma unroll
    for (int mt = 0; mt < 4; ++mt) {
      ah[mt] = *(const bs8*)(Ahi + (mt * 16 + ln) * HH + sb);
      al[mt] = *(const bs8*)(Alo + (mt * 16 + ln) * HH + sb);
    }
#pragma unroll
    for (int mt = 0; mt < 4; ++mt)
#pragma unroll
      for (int nt = 0; nt < 2; ++nt) {
        acc[mt][nt] = __builtin_amdgcn_mfma_f32_16x16x32_bf16(al[mt], bh[nt], acc[mt][nt], 0, 0, 0);
        acc[mt][nt] = __builtin_amdgcn_mfma_f32_16x16x32_bf16(ah[mt], bl[nt], acc[mt][nt], 0, 0, 0);
        acc[mt][nt] = __builtin_amdgcn_mfma_f32_16x16x32_bf16(ah[mt], bh[nt], acc[mt][nt], 0, 0, 0);
      }
  }
  // epilogue: outer gelu
#pragma unroll
  for (int nt = 0; nt < 2; ++nt) {
    int col = (wq * 2 + nt) * 16 + ln;
    float bb = b2[col];
#pragma unroll
    for (int mt = 0; mt < 4; ++mt)
#pragma unroll
      for (int r = 0; r < 4; ++r) {
        float o = gelu_f(acc[mt][nt][r] + bb);
        out[(size_t)(row0 + mt * 16 + quad * 4 + r) * HH + col] = o;
      }
  }
}

// ---------------- final MLP + fused masked-sum pooling ----------------------------
// Same GEMM1-direct surgery as mlp_kernel; pool path (padded LDSA tile, Tf overlay,
// kk run-length atomics) unchanged. Barriers: t-stage, post-GEMM2, Tf-staged.
__global__ __launch_bounds__(256, 4) void mlp_pool_kernel(
    const float* __restrict__ in,
    const unsigned short* __restrict__ w1hi, const unsigned short* __restrict__ w1lo,
    const float* __restrict__ b1,
    const unsigned short* __restrict__ w2hi, const unsigned short* __restrict__ w2lo,
    const float* __restrict__ b2,
    const float* __restrict__ nmask, const int* __restrict__ batch,
    float* __restrict__ num) {
  __shared__ __align__(16) unsigned short AB[128 * LDSA];
  __shared__ int kk[64];
  unsigned short* Ahi = AB;
  unsigned short* Alo = AB + 64 * LDSA;
  int tid = threadIdx.x;
  int row0 = blockIdx.x * 64;
  int lane = tid & 63, wq = tid >> 6;
  int ln = lane & 15, quad = lane >> 4;

  if (tid < 64) {
    int gr = row0 + tid;
    int c = gr / NN;
    int n = gr - c * NN;
    kk[tid] = (c << 6) | batch[n];
  }

  f32x4 acc[4][2];
#pragma unroll
  for (int mt = 0; mt < 4; ++mt)
#pragma unroll
    for (int nt = 0; nt < 2; ++nt)
#pragma unroll
      for (int r = 0; r < 4; ++r) acc[mt][nt][r] = 0.f;

  // GEMM1, A direct from global
#pragma unroll
  for (int ks = 0; ks < 4; ++ks) {
    bs8 bh[2], bl[2];
#pragma unroll
    for (int nt = 0; nt < 2; ++nt) {
      int wrow = ((wq * 2 + nt) * 16 + ln) * HH + ks * 32 + quad * 8;
      bh[nt] = *(const bs8*)(w1hi + wrow);
      bl[nt] = *(const bs8*)(w1lo + wrow);
    }
#pragma unroll
    for (int mt = 0; mt < 4; ++mt) {
      const float* p = in + (size_t)(row0 + mt * 16 + ln) * HH + ks * 32 + quad * 8;
      f32x4 v0 = __builtin_nontemporal_load((const f32x4*)p);
      f32x4 v1 = __builtin_nontemporal_load((const f32x4*)(p + 4));
      bs8 ah, al;
      cvt_hi_lo(v0, v1, ah, al);
#pragma unroll
      for (int nt = 0; nt < 2; ++nt) {
        acc[mt][nt] = __builtin_amdgcn_mfma_f32_16x16x32_bf16(al, bh[nt], acc[mt][nt], 0, 0, 0);
        acc[mt][nt] = __builtin_amdgcn_mfma_f32_16x16x32_bf16(ah, bl[nt], acc[mt][nt], 0, 0, 0);
        acc[mt][nt] = __builtin_amdgcn_mfma_f32_16x16x32_bf16(ah, bh[nt], acc[mt][nt], 0, 0, 0);
      }
    }
  }

  // t = gelu(acc + b1) -> padded LDS hi/lo
#pragma unroll
  for (int nt = 0; nt < 2; ++nt) {
    int col = (wq * 2 + nt) * 16 + ln;
    float bb = b1[col];
#pragma unroll
    for (int mt = 0; mt < 4; ++mt)
#pragma unroll
      for (int r = 0; r < 4; ++r) {
        float tv = gelu_f(acc[mt][nt][r] + bb);
        unsigned short th = f2bf(tv);
        int rr = mt * 16 + quad * 4 + r;
        Ahi[rr * LDSA + col] = th;
        Alo[rr * LDSA + col] = f2bf(tv - bf2f(th));
      }
  }
  __syncthreads();  // B3: t staged (also publishes kk)

#pragma unroll
  for (int mt = 0; mt < 4; ++mt)
#pragma unroll
    for (int nt = 0; nt < 2; ++nt)
#pragma unroll
      for (int r = 0; r < 4; ++r) acc[mt][nt][r] = 0.f;
#pragma unroll
  for (int ks = 0; ks < 4; ++ks) {
    bs8 bh[2], bl[2];
#pragma unroll
    for (int nt = 0; nt < 2; ++nt) {
      int wrow = ((wq * 2 + nt) * 16 + ln) * HH + ks * 32 + quad * 8;
      bh[nt] = *(const bs8*)(w2hi + wrow);
      bl[nt] = *(const bs8*)(w2lo + wrow);
    }
    bs8 ah[4], al[4];
#pragma unroll
    for (int mt = 0; mt < 4; ++mt) {
      ah[mt] = *(const bs8*)(Ahi + (mt * 16 + ln) * LDSA + ks * 32 + quad * 8);
      al[mt] = *(const bs8*)(Alo + (mt * 16 + ln) * LDSA + ks * 32 + quad * 8);
    }
#pragma unroll
    for (int mt = 0; mt < 4; ++mt)
#pragma unroll
      for (int nt = 0; nt < 2; ++nt) {
        acc[mt][nt] = __builtin_amdgcn_mfma_f32_16x16x32_bf16(al[mt], bh[nt], acc[mt][nt], 0, 0, 0);
        acc[mt][nt] = __builtin_amdgcn_mfma_f32_16x16x32_bf16(ah[mt], bl[nt], acc[mt][nt], 0, 0, 0);
        acc[mt][nt] = __builtin_amdgcn_mfma_f32_16x16x32_bf16(ah[mt], bh[nt], acc[mt][nt], 0, 0, 0);
      }
  }
  __syncthreads();  // B4: GEMM2 LDS reads done before Tf overlay
  float* Tf = (float*)AB;
#pragma unroll
  for (int nt = 0; nt < 2; ++nt) {
    int col = (wq * 2 + nt) * 16 + ln;
    float bb = b2[col];
#pragma unroll
    for (int mt = 0; mt < 4; ++mt)
#pragma unroll
      for (int r = 0; r < 4; ++r) {
        int rl = mt * 16 + quad * 4 + r;
        int gr = row0 + rl;
        Tf[rl * LDSF + col] = (acc[mt][nt][r] + bb) * nmask[gr];
      }
  }
  __syncthreads();  // B5
  if (tid < 128) {
    int col = tid;
    float a2 = 0.f;
    int cur = kk[0];
    for (int r = 0; r < 64; ++r) {
      int k2 = kk[r];
      if (k2 != cur) {
        atomicAdd(&num[((size_t)(cur & 63) * CC + (cur >> 6)) * HH + col], a2);
        a2 = 0.f;
        cur = k2;
      }
      a2 += Tf[r * LDSF + col];
    }
    atomicAdd(&num[((size_t)(cur & 63) * CC + (cur >> 6)) * HH + col], a2);
  }
}

// ---------------- pool finalize ----------------
__global__ __launch_bounds__(256) void pool_finalize_kernel(const float* __restrict__ num,
                                                            const int* __restrict__ batch,
                                                            const float* __restrict__ nmask,
                                                            float* __restrict__ outp) {
  int g = blockIdx.x >> 2, c = blockIdx.x & 3;
  int lo = 0, hi = NN;
  while (lo < hi) { int m = (lo + hi) >> 1; if (batch[m] < g) lo = m + 1; else hi = m; }
  int start = lo;
  hi = NN;
  while (lo < hi) { int m = (lo + hi) >> 1; if (batch[m] < g + 1) lo = m + 1; else hi = m; }
  int end = lo;
  int tid = threadIdx.x;
  float d = 0.f;
  for (int n = start + tid; n < end; n += 256) d += nmask[c * NN + n];
#pragma unroll
  for (int k = 1; k < 64; k <<= 1) d += __shfl_xor(d, k);
  __shared__ float ws4[4];
  if ((tid & 63) == 0) ws4[tid >> 6] = d;
  __syncthreads();
  float den = ws4[0] + ws4[1] + ws4[2] + ws4[3] + 1e-7f;
  if (tid < 128) {
    int idx = blockIdx.x * 128 + tid;
    outp[idx] = num[idx] / den;
  }
}

extern "C" void kernel_launch(void* const* d_in, const int* in_sizes, int n_in,
                              void* d_out, int out_size, void* d_ws, size_t ws_size,
                              hipStream_t stream) {
  const float* x_in  = (const float*)d_in[0];
  const int*   batch = (const int*)d_in[1];
  const int*   eidx  = (const int*)d_in[2];
  const float* eattr = (const float*)d_in[3];
  const float* nmask = (const float*)d_in[4];
  const float* emask = (const float*)d_in[5];
  const float* Wbe   = (const float*)d_in[6];
  const float* bbe   = (const float*)d_in[7];
  const float* epsp  = (const float*)d_in[8];
  const float* W1    = (const float*)d_in[9];
  const float* b1    = (const float*)d_in[10];
  const float* W2    = (const float*)d_in[11];
  const float* b2    = (const float*)d_in[12];
  const float* Wm1   = (const float*)d_in[13];
  const float* bm1   = (const float*)d_in[14];
  const float* Wm2   = (const float*)d_in[15];
  const float* bm2   = (const float*)d_in[16];
  float* outp = (float*)d_out;

  const int* srcp = eidx;
  const int* dstp = eidx + EN;

  char* ws = (char*)d_ws;
  float* ee   = (float*)(ws);                  // 102,400,000 B
  float* hbuf = (float*)(ws + 102400000);
  float* xbuf = (float*)(ws + 204800000);
  int* counts  = (int*)(ws + 307200000);       // 200,000 B
  int* offsets = (int*)(ws + 307400000);       // 200,004 B
  int* cursor  = (int*)(ws + 307600008);       // 200,000 B
  int2* csr_es = (int2*)(ws + 307800016);      // 1,600,000 B (8-aligned)
  float4* emask_s = (float4*)(ws + 309400016); // 3,200,000 B (16-aligned)
  unsigned short* wts = (unsigned short*)(ws + 312600016);  // 12*32768 B
  int* bsums = (int*)ws;                 // overlay: before ee_kernel writes ee
  int* boffs = (int*)(ws + 1024);
  float* num = (float*)ws;               // overlay: after last ee read

  const int NB = (NN + 255) / 256;  // 196

  hipMemsetAsync(counts, 0, NN * sizeof(int), stream);
  count_kernel<<<(EN + 255) / 256, 256, 0, stream>>>(dstp, counts);
  block_sum_kernel<<<NB, 256, 0, stream>>>(counts, bsums);
  bsum_scan_kernel<<<1, 256, 0, stream>>>(bsums, boffs, NB);
  block_scan_kernel<<<NB, 256, 0, stream>>>(counts, boffs, offsets, cursor);
  fill_kernel<<<(EN + 255) / 256, 256, 0, stream>>>(dstp, srcp, emask, cursor, csr_es, emask_s);

  prep_w_kernel<<<384, 256, 0, stream>>>(W1, W2, Wm1, Wm2, wts);

  ee_kernel<<<EN / 16, 256, 0, stream>>>(eattr, Wbe, bbe, ee);

  // layer 0
  agg_kernel<<<NN / 4, 256, 0, stream>>>(x_in, ee, offsets, csr_es, emask_s, epsp, 0, hbuf);
  mlp_kernel<<<(CC * NN) / 64, 256, 0, stream>>>(hbuf, wts + 0, wts + 16384, b1,
                                                 wts + 65536, wts + 81920, b2, xbuf);
  // layer 1
  agg_kernel<<<NN / 4, 256, 0, stream>>>(xbuf, ee, offsets, csr_es, emask_s, epsp, 1, hbuf);
  mlp_kernel<<<(CC * NN) / 64, 256, 0, stream>>>(hbuf, wts + 32768, wts + 49152, b1 + 128,
                                                 wts + 98304, wts + 114688, b2 + 128, xbuf);
  // final node MLP with fused masked-sum pooling
  hipMemsetAsync(num, 0, 131072, stream);
  mlp_pool_kernel<<<(CC * NN) / 64, 256, 0, stream>>>(xbuf, wts + 131072, wts + 147456, bm1,
                                                      wts + 163840, wts + 180224, bm2,
                                                      nmask, batch, num);
  pool_finalize_kernel<<<GG * CC, 256, 0, stream>>>(num, batch, nmask, outp);
}

// Round 6
// 742.958 us; speedup vs baseline: 1.1636x; 1.1636x over previous
//
#include <hip/hip_runtime.h>
#include <math.h>

#define NN 50000
#define EN 200000
#define CC 4
#define HH 128
#define GG 64
#define LDSA 136   // padded stride for pool-variant tile
#define LDSF 132   // f32 stride for fused-pool tile
#define NTILE 3125 // CC*NN/64
#define HTILE 1563 // ceil(NTILE/2)

typedef __attribute__((ext_vector_type(8))) short bs8;
typedef __attribute__((ext_vector_type(4))) float f32x4;
typedef __attribute__((ext_vector_type(2))) float f32x2;

__device__ __forceinline__ unsigned short f2bf(float f) {
  unsigned int u = __float_as_uint(f);
  u += 0x7FFFu + ((u >> 16) & 1u);
  return (unsigned short)(u >> 16);
}
__device__ __forceinline__ float bf2f(unsigned short h) {
  return __uint_as_float(((unsigned int)h) << 16);
}
__device__ __forceinline__ void cvt_hi_lo(const f32x4& v0, const f32x4& v1, bs8& h, bs8& l) {
  h[0] = f2bf(v0[0]); h[1] = f2bf(v0[1]); h[2] = f2bf(v0[2]); h[3] = f2bf(v0[3]);
  h[4] = f2bf(v1[0]); h[5] = f2bf(v1[1]); h[6] = f2bf(v1[2]); h[7] = f2bf(v1[3]);
  l[0] = f2bf(v0[0] - bf2f(h[0])); l[1] = f2bf(v0[1] - bf2f(h[1]));
  l[2] = f2bf(v0[2] - bf2f(h[2])); l[3] = f2bf(v0[3] - bf2f(h[3]));
  l[4] = f2bf(v1[0] - bf2f(h[4])); l[5] = f2bf(v1[1] - bf2f(h[5]));
  l[6] = f2bf(v1[2] - bf2f(h[6])); l[7] = f2bf(v1[3] - bf2f(h[7]));
}
// fast erf-GELU: A&S 7.1.26 minimax (|erf err| ~1.5e-7) + hw rcp/exp
__device__ __forceinline__ float gelu_f(float x) {
  float z = fabsf(x) * 0.7071067811865476f;
  float t = __builtin_amdgcn_rcpf(fmaf(0.3275911f, z, 1.0f));
  float poly = t * fmaf(t, fmaf(t, fmaf(t, fmaf(t, 1.061405429f, -1.453152027f),
                                        1.421413741f), -0.284496736f), 0.254829592f);
  float e = fmaf(-poly, __expf(-z * z), 1.0f);
  return 0.5f * x * (1.0f + copysignf(e, x));
}
// 2*gelu(x) — caller pre-folds the 0.5 into the edge mask
__device__ __forceinline__ float gelu2_f(float x) {
  float z = fabsf(x) * 0.7071067811865476f;
  float t = __builtin_amdgcn_rcpf(fmaf(0.3275911f, z, 1.0f));
  float poly = t * fmaf(t, fmaf(t, fmaf(t, fmaf(t, 1.061405429f, -1.453152027f),
                                        1.421413741f), -0.284496736f), 0.254829592f);
  float e = fmaf(-poly, __expf(-z * z), 1.0f);
  return x * (1.0f + copysignf(e, x));
}

// ---------------- CSR build ----------------
__global__ __launch_bounds__(256) void count_kernel(const int* __restrict__ dst,
                                                    int* __restrict__ counts) {
  int e = blockIdx.x * 256 + threadIdx.x;
  if (e < EN) atomicAdd(&counts[dst[e]], 1);
}

__global__ __launch_bounds__(256) void block_sum_kernel(const int* __restrict__ counts,
                                                        int* __restrict__ bsums) {
  int tid = threadIdx.x;
  int i = blockIdx.x * 256 + tid;
  int v = (i < NN) ? counts[i] : 0;
#pragma unroll
  for (int d = 1; d < 64; d <<= 1) v += __shfl_xor(v, d);
  __shared__ int ws4[4];
  if ((tid & 63) == 0) ws4[tid >> 6] = v;
  __syncthreads();
  if (tid == 0) bsums[blockIdx.x] = ws4[0] + ws4[1] + ws4[2] + ws4[3];
}

__global__ __launch_bounds__(256) void bsum_scan_kernel(const int* __restrict__ bsums,
                                                        int* __restrict__ boffs, int nb) {
  int tid = threadIdx.x, lane = tid & 63, wv = tid >> 6;
  int v = (tid < nb) ? bsums[tid] : 0;
  int s = v;
#pragma unroll
  for (int d = 1; d < 64; d <<= 1) { int t = __shfl_up(s, d); if (lane >= d) s += t; }
  __shared__ int wsum[4];
  if (lane == 63) wsum[wv] = s;
  __syncthreads();
  int pre = 0;
  for (int j = 0; j < wv; ++j) pre += wsum[j];
  if (tid < nb) boffs[tid] = pre + s - v;
}

__global__ __launch_bounds__(256) void block_scan_kernel(const int* __restrict__ counts,
                                                         const int* __restrict__ boffs,
                                                         int* __restrict__ offsets,
                                                         int* __restrict__ cursor) {
  int tid = threadIdx.x, lane = tid & 63, wv = tid >> 6;
  int i = blockIdx.x * 256 + tid;
  int v = (i < NN) ? counts[i] : 0;
  int s = v;
#pragma unroll
  for (int d = 1; d < 64; d <<= 1) { int t = __shfl_up(s, d); if (lane >= d) s += t; }
  __shared__ int wsum[4];
  if (lane == 63) wsum[wv] = s;
  __syncthreads();
  int pre = boffs[blockIdx.x];
  for (int j = 0; j < wv; ++j) pre += wsum[j];
  if (i < NN) { int e = pre + s - v; offsets[i] = e; cursor[i] = e; }
  if (i == 0) offsets[NN] = EN;
}

// fill: CSR-ordered side arrays (kills dependent index chain + emask line waste)
__global__ __launch_bounds__(256) void fill_kernel(const int* __restrict__ dst,
                                                   const int* __restrict__ src,
                                                   const float* __restrict__ emask,
                                                   int* __restrict__ cursor,
                                                   int2* __restrict__ csr_es,
                                                   float4* __restrict__ emask_s) {
  int e = blockIdx.x * 256 + threadIdx.x;
  if (e < EN) {
    int s = src[e];
    float m0 = emask[e];
    float m1 = emask[EN + e];
    float m2 = emask[2 * EN + e];
    float m3 = emask[3 * EN + e];
    int pos = atomicAdd(&cursor[dst[e]], 1);
    csr_es[pos] = make_int2(e, s);
    emask_s[pos] = make_float4(m0, m1, m2, m3);
  }
}

// ---------------- weight prep: transpose + hi/lo bf16 split ----------------------
__global__ __launch_bounds__(256) void prep_w_kernel(const float* __restrict__ W1,
                                                     const float* __restrict__ W2,
                                                     const float* __restrict__ Wm1,
                                                     const float* __restrict__ Wm2,
                                                     unsigned short* __restrict__ wts) {
  int m = blockIdx.x >> 6;
  int idx = (blockIdx.x & 63) * 256 + threadIdx.x;  // 0..16383
  const float* src = (m == 0) ? W1 : (m == 1) ? W1 + 16384 : (m == 2) ? W2
                     : (m == 3) ? W2 + 16384 : (m == 4) ? Wm1 : Wm2;
  unsigned short* dhi = wts + m * 32768;
  unsigned short* dlo = dhi + 16384;
  int n = idx >> 7, k = idx & 127;
  float v = src[k * HH + n];  // src [k][n] -> dst [n][k]
  unsigned short hi = f2bf(v);
  dhi[n * HH + k] = hi;
  dlo[n * HH + k] = f2bf(v - bf2f(hi));
}

// ---------------- bond encoder: 16 edges per block ----------------
__global__ __launch_bounds__(256) void ee_kernel(const float* __restrict__ eattr,
                                                 const float* __restrict__ Wbe,
                                                 const float* __restrict__ bbe,
                                                 float* __restrict__ ee) {
  __shared__ float Ws[16 * HH];
  __shared__ float Ea[16 * 16];
  int tid = threadIdx.x;
  int e0 = blockIdx.x * 16;
#pragma unroll
  for (int i = 0; i < 8; ++i) Ws[tid + i * 256] = Wbe[tid + i * 256];
  Ea[tid] = eattr[(size_t)e0 * 16 + tid];
  __syncthreads();
  int h = tid & 127, half = tid >> 7;
  float bb = bbe[h];
#pragma unroll
  for (int j = 0; j < 8; ++j) {
    int el = j * 2 + half;
    float acc = bb;
#pragma unroll
    for (int d = 0; d < 16; ++d) acc += Ea[el * 16 + d] * Ws[d * HH + h];
    ee[(size_t)(e0 + el) * HH + h] = acc;
  }
}

// ---- message aggregation: one wave per node, one edge per wave (float2/lane).
// Depth-3 software pipeline: edges t (compute), t+1, t+2 (data in flight), t+3
// (index in flight). Per-edge compute ~200cy vs gather ~300-500cy -> depth 2 was
// insufficient (R3: VALUBusy 49%). hout nt-stored so x/ee stay L3-resident.
__global__ __launch_bounds__(256) void agg_kernel(const float* __restrict__ x,
                                                  const float* __restrict__ ee,
                                                  const int* __restrict__ off,
                                                  const int2* __restrict__ csr_es,
                                                  const float4* __restrict__ emask_s,
                                                  const float* __restrict__ epsp, int layer,
                                                  float* __restrict__ hout) {
  int wv = threadIdx.x >> 6, lane = threadIdx.x & 63;
  int v = blockIdx.x * 4 + wv;
  int c2 = lane * 2;
  float2 acc[CC];
#pragma unroll
  for (int c = 0; c < CC; ++c) { acc[c].x = 0.f; acc[c].y = 0.f; }
  int beg = off[v], end = off[v + 1];

  float2 eeC, eeB;
  float2 xC[CC], xB[CC];
  float emC[CC], emB[CC];
  int2 es2 = make_int2(0, 0), es3 = make_int2(0, 0);
  eeC.x = eeC.y = eeB.x = eeB.y = 0.f;
#pragma unroll
  for (int c = 0; c < CC; ++c) {
    xC[c].x = xC[c].y = xB[c].x = xB[c].y = 0.f;
    emC[c] = emB[c] = 0.f;
  }

  if (beg < end) {
    int2 e0 = csr_es[beg];
    eeC = *(const float2*)(ee + (size_t)e0.x * HH + c2);
#pragma unroll
    for (int c = 0; c < CC; ++c)
      xC[c] = *(const float2*)(x + ((size_t)c * NN + e0.y) * HH + c2);
    float4 m = emask_s[beg];
    emC[0] = 0.5f * m.x; emC[1] = 0.5f * m.y; emC[2] = 0.5f * m.z; emC[3] = 0.5f * m.w;
  }
  if (beg + 1 < end) {
    int2 e1 = csr_es[beg + 1];
    eeB = *(const float2*)(ee + (size_t)e1.x * HH + c2);
#pragma unroll
    for (int c = 0; c < CC; ++c)
      xB[c] = *(const float2*)(x + ((size_t)c * NN + e1.y) * HH + c2);
    float4 m = emask_s[beg + 1];
    emB[0] = 0.5f * m.x; emB[1] = 0.5f * m.y; emB[2] = 0.5f * m.z; emB[3] = 0.5f * m.w;
  }
  if (beg + 2 < end) es2 = csr_es[beg + 2];

  for (int t = beg; t < end; ++t) {
    float2 eeD;
    float2 xD[CC];
    float emD[CC];
    if (t + 2 < end) {
      eeD = *(const float2*)(ee + (size_t)es2.x * HH + c2);
#pragma unroll
      for (int c = 0; c < CC; ++c)
        xD[c] = *(const float2*)(x + ((size_t)c * NN + es2.y) * HH + c2);
      float4 m = emask_s[t + 2];
      emD[0] = 0.5f * m.x; emD[1] = 0.5f * m.y; emD[2] = 0.5f * m.z; emD[3] = 0.5f * m.w;
      es3 = (t + 3 < end) ? csr_es[t + 3] : make_int2(0, 0);
    } else {
      eeD.x = eeD.y = 0.f;
#pragma unroll
      for (int c = 0; c < CC; ++c) { xD[c].x = xD[c].y = 0.f; emD[c] = 0.f; }
      es3 = make_int2(0, 0);
    }
    // compute edge t
#pragma unroll
    for (int c = 0; c < CC; ++c) {
      acc[c].x += gelu2_f(xC[c].x + eeC.x) * emC[c];
      acc[c].y += gelu2_f(xC[c].y + eeC.y) * emC[c];
    }
    // rotate
    eeC = eeB; eeB = eeD;
#pragma unroll
    for (int c = 0; c < CC; ++c) {
      xC[c] = xB[c]; xB[c] = xD[c];
      emC[c] = emB[c]; emB[c] = emD[c];
    }
    es2 = es3;
  }

  float ep = 1.0f + epsp[layer];
#pragma unroll
  for (int c = 0; c < CC; ++c) {
    float2 xs = *(const float2*)(x + ((size_t)c * NN + v) * HH + c2);
    f32x2 o;
    o[0] = fmaf(ep, xs.x, acc[c].x);
    o[1] = fmaf(ep, xs.y, acc[c].y);
    __builtin_nontemporal_store(o, (f32x2*)(hout + ((size_t)c * NN + v) * HH + c2));
  }
}

// ---------------- MLP helpers (R3 structure factored) ----------------------------
__device__ __forceinline__ void loadW(const unsigned short* __restrict__ whi,
                                      const unsigned short* __restrict__ wlo,
                                      bs8 (&bh)[4][2], bs8 (&bl)[4][2],
                                      int ln, int quad, int wq) {
#pragma unroll
  for (int ks = 0; ks < 4; ++ks)
#pragma unroll
    for (int nt = 0; nt < 2; ++nt) {
      int wrow = ((wq * 2 + nt) * 16 + ln) * HH + ks * 32 + quad * 8;
      bh[ks][nt] = *(const bs8*)(whi + wrow);
      bl[ks][nt] = *(const bs8*)(wlo + wrow);
    }
}
__device__ __forceinline__ void zacc(f32x4 (&acc)[4][2]) {
#pragma unroll
  for (int mt = 0; mt < 4; ++mt)
#pragma unroll
    for (int nt = 0; nt < 2; ++nt)
#pragma unroll
      for (int r = 0; r < 4; ++r) acc[mt][nt][r] = 0.f;
}
// 3-term GEMM over XOR-swizzled 64xHH LDS tile with preloaded W frags
__device__ __forceinline__ void gemm3(const unsigned short* Ahi, const unsigned short* Alo,
                                      const bs8 (&bh)[4][2], const bs8 (&bl)[4][2],
                                      f32x4 (&acc)[4][2], int ln, int quad) {
#pragma unroll
  for (int ks = 0; ks < 4; ++ks) {
    bs8 ah[4], al[4];
    int sb = ((ks * 4 + quad) ^ ln) * 8;
#pragma unroll
    for (int mt = 0; mt < 4; ++mt) {
      ah[mt] = *(const bs8*)(Ahi + (mt * 16 + ln) * HH + sb);
      al[mt] = *(const bs8*)(Alo + (mt * 16 + ln) * HH + sb);
    }
#pragma unroll
    for (int nt = 0; nt < 2; ++nt)
#pragma unroll
      for (int mt = 0; mt < 4; ++mt) {
        acc[mt][nt] = __builtin_amdgcn_mfma_f32_16x16x32_bf16(al[mt], bh[ks][nt], acc[mt][nt], 0, 0, 0);
        acc[mt][nt] = __builtin_amdgcn_mfma_f32_16x16x32_bf16(ah[mt], bl[ks][nt], acc[mt][nt], 0, 0, 0);
        acc[mt][nt] = __builtin_amdgcn_mfma_f32_16x16x32_bf16(ah[mt], bh[ks][nt], acc[mt][nt], 0, 0, 0);
      }
  }
}
// t = gelu(acc+b1) -> swizzled LDS hi/lo
__device__ __forceinline__ void tstage(unsigned short* Ahi, unsigned short* Alo,
                                       const float* __restrict__ b1v, f32x4 (&acc)[4][2],
                                       int ln, int quad, int wq) {
#pragma unroll
  for (int nt = 0; nt < 2; ++nt) {
    int col = (wq * 2 + nt) * 16 + ln;
    int cb = col >> 3, co = col & 7;
    float bb = b1v[col];
#pragma unroll
    for (int mt = 0; mt < 4; ++mt)
#pragma unroll
      for (int r = 0; r < 4; ++r) {
        float tv = gelu_f(acc[mt][nt][r] + bb);
        unsigned short th = f2bf(tv);
        int rr = mt * 16 + quad * 4 + r;
        int sof = rr * HH + (cb ^ (rr & 15)) * 8 + co;
        Ahi[sof] = th;
        Alo[sof] = f2bf(tv - bf2f(th));
      }
  }
}
__device__ __forceinline__ void epilog(float* __restrict__ out, const float* __restrict__ b2v,
                                       f32x4 (&acc)[4][2], int row0, int ln, int quad, int wq) {
#pragma unroll
  for (int nt = 0; nt < 2; ++nt) {
    int col = (wq * 2 + nt) * 16 + ln;
    float bb = b2v[col];
#pragma unroll
    for (int mt = 0; mt < 4; ++mt)
#pragma unroll
      for (int r = 0; r < 4; ++r) {
        float o = gelu_f(acc[mt][nt][r] + bb);
        out[(size_t)(row0 + mt * 16 + quad * 4 + r) * HH + col] = o;
      }
  }
}

// ---------------- MLP: 2 tiles/block, async-stage pipeline -----------------------
// Block b runs tiles {b, b+HTILE}. Tile1's 8 global A-loads are issued right after
// the first barrier and consumed only after tile0's GEMM1->t->GEMM2 (~3000cy) —
// full latency blanket (R4's inline-load failure done right: bulk prefetch to regs,
// bulk convert+LDS-write later). Same 32KB LDS as R3; +1 barrier per 2 tiles.
__global__ __launch_bounds__(256, 2) void mlp_kernel(
    const float* __restrict__ in,
    const unsigned short* __restrict__ w1hi, const unsigned short* __restrict__ w1lo,
    const float* __restrict__ b1,
    const unsigned short* __restrict__ w2hi, const unsigned short* __restrict__ w2lo,
    const float* __restrict__ b2,
    float* __restrict__ out) {
  __shared__ __align__(16) unsigned short AB[2 * 64 * HH];
  unsigned short* Ahi = AB;
  unsigned short* Alo = AB + 64 * HH;
  int tid = threadIdx.x;
  int lane = tid & 63, wq = tid >> 6;
  int ln = lane & 15, quad = lane >> 4;
  int t1 = blockIdx.x + HTILE;
  bool has2 = (t1 < NTILE);
  int row0 = blockIdx.x * 64;
  int row1 = t1 * 64;

  bs8 w1h[4][2], w1l[4][2];
  loadW(w1hi, w1lo, w1h, w1l, ln, quad, wq);
  // stage tile0 -> LDS (bulk coalesced, R3 pattern)
#pragma unroll
  for (int i = 0; i < 4; ++i) {
    int idx = tid + i * 256;
    int r = idx >> 4, blk = idx & 15;
    const float* p = in + (size_t)(row0 + r) * HH + blk * 8;
    f32x4 v0 = __builtin_nontemporal_load((const f32x4*)p);
    f32x4 v1 = __builtin_nontemporal_load((const f32x4*)(p + 4));
    bs8 h, l;
    cvt_hi_lo(v0, v1, h, l);
    int sb = blk ^ (r & 15);
    *(bs8*)(Ahi + r * HH + sb * 8) = h;
    *(bs8*)(Alo + r * HH + sb * 8) = l;
  }
  __syncthreads();  // W0: tile0 A staged

  // issue tile1 A-loads now; first use is after tile0's GEMM2
  f32x4 pa[4], pb[4];
  if (has2) {
#pragma unroll
    for (int i = 0; i < 4; ++i) {
      int idx = tid + i * 256;
      int r = idx >> 4, blk = idx & 15;
      const float* p = in + (size_t)(row1 + r) * HH + blk * 8;
      pa[i] = __builtin_nontemporal_load((const f32x4*)p);
      pb[i] = __builtin_nontemporal_load((const f32x4*)(p + 4));
    }
  }

  f32x4 acc[4][2];
  zacc(acc);
  gemm3(Ahi, Alo, w1h, w1l, acc, ln, quad);
  __syncthreads();  // X0: GEMM1 LDS reads done

  bs8 w2h[4][2], w2l[4][2];
  loadW(w2hi, w2lo, w2h, w2l, ln, quad, wq);
  tstage(Ahi, Alo, b1, acc, ln, quad, wq);
  __syncthreads();  // Y0: t staged

  zacc(acc);
  gemm3(Ahi, Alo, w2h, w2l, acc, ln, quad);
  epilog(out, b2, acc, row0, ln, quad, wq);

  if (!has2) return;
  __syncthreads();  // Z: tile0 GEMM2 LDS reads done
  loadW(w1hi, w1lo, w1h, w1l, ln, quad, wq);
#pragma unroll
  for (int i = 0; i < 4; ++i) {
    int idx = tid + i * 256;
    int r = idx >> 4, blk = idx & 15;
    bs8 h, l;
    cvt_hi_lo(pa[i], pb[i], h, l);
    int sb = blk ^ (r & 15);
    *(bs8*)(Ahi + r * HH + sb * 8) = h;
    *(bs8*)(Alo + r * HH + sb * 8) = l;
  }
  __syncthreads();  // W1: tile1 A staged

  zacc(acc);
  gemm3(Ahi, Alo, w1h, w1l, acc, ln, quad);
  __syncthreads();  // X1

  loadW(w2hi, w2lo, w2h, w2l, ln, quad, wq);
  tstage(Ahi, Alo, b1, acc, ln, quad, wq);
  __syncthreads();  // Y1

  zacc(acc);
  gemm3(Ahi, Alo, w2h, w2l, acc, ln, quad);
  epilog(out, b2, acc, row1, ln, quad, wq);
}

// ---------------- final MLP + fused masked-sum pooling (R3 proven form) ----------
__global__ __launch_bounds__(256, 2) void mlp_pool_kernel(
    const float* __restrict__ in,
    const unsigned short* __restrict__ w1hi, const unsigned short* __restrict__ w1lo,
    const float* __restrict__ b1,
    const unsigned short* __restrict__ w2hi, const unsigned short* __restrict__ w2lo,
    const float* __restrict__ b2,
    const float* __restrict__ nmask, const int* __restrict__ batch,
    float* __restrict__ num) {
  __shared__ __align__(16) unsigned short AB[128 * LDSA];
  __shared__ int kk[64];
  unsigned short* Ahi = AB;
  unsigned short* Alo = AB + 64 * LDSA;
  int tid = threadIdx.x;
  int row0 = blockIdx.x * 64;
  int lane = tid & 63, wq = tid >> 6;
  int ln = lane & 15, quad = lane >> 4;

  bs8 b1h[4][2], b1l[4][2];
  loadW(w1hi, w1lo, b1h, b1l, ln, quad, wq);
#pragma unroll
  for (int i = 0; i < 8; ++i) {
    int idx = tid + i * 256;
    int r = idx >> 5, cc4 = idx & 31;
    f32x4 vv = __builtin_nontemporal_load(
        (const f32x4*)(in + (size_t)(row0 + r) * HH + cc4 * 4));
    unsigned short h0 = f2bf(vv[0]), h1 = f2bf(vv[1]), h2 = f2bf(vv[2]), h3 = f2bf(vv[3]);
    ushort4 hv; hv.x = h0; hv.y = h1; hv.z = h2; hv.w = h3;
    ushort4 lv;
    lv.x = f2bf(vv[0] - bf2f(h0)); lv.y = f2bf(vv[1] - bf2f(h1));
    lv.z = f2bf(vv[2] - bf2f(h2)); lv.w = f2bf(vv[3] - bf2f(h3));
    *(ushort4*)(Ahi + r * LDSA + cc4 * 4) = hv;
    *(ushort4*)(Alo + r * LDSA + cc4 * 4) = lv;
  }
  if (tid < 64) {
    int gr = row0 + tid;
    int c = gr / NN;
    int n = gr - c * NN;
    kk[tid] = (c << 6) | batch[n];
  }
  __syncthreads();  // B1

  f32x4 acc[4][2];
  zacc(acc);
#pragma unroll
  for (int ks = 0; ks < 4; ++ks) {
    bs8 ah[4], al[4];
#pragma unroll
    for (int mt = 0; mt < 4; ++mt) {
      ah[mt] = *(const bs8*)(Ahi + (mt * 16 + ln) * LDSA + ks * 32 + quad * 8);
      al[mt] = *(const bs8*)(Alo + (mt * 16 + ln) * LDSA + ks * 32 + quad * 8);
    }
#pragma unroll
    for (int nt = 0; nt < 2; ++nt)
#pragma unroll
      for (int mt = 0; mt < 4; ++mt) {
        acc[mt][nt] = __builtin_amdgcn_mfma_f32_16x16x32_bf16(al[mt], b1h[ks][nt], acc[mt][nt], 0, 0, 0);
        acc[mt][nt] = __builtin_amdgcn_mfma_f32_16x16x32_bf16(ah[mt], b1l[ks][nt], acc[mt][nt], 0, 0, 0);
        acc[mt][nt] = __builtin_amdgcn_mfma_f32_16x16x32_bf16(ah[mt], b1h[ks][nt], acc[mt][nt], 0, 0, 0);
      }
  }
  __syncthreads();  // B2

  bs8 b2h[4][2], b2l[4][2];
  loadW(w2hi, w2lo, b2h, b2l, ln, quad, wq);
#pragma unroll
  for (int nt = 0; nt < 2; ++nt) {
    int col = (wq * 2 + nt) * 16 + ln;
    float bb = b1[col];
#pragma unroll
    for (int mt = 0; mt < 4; ++mt)
#pragma unroll
      for (int r = 0; r < 4; ++r) {
        float tv = gelu_f(acc[mt][nt][r] + bb);
        unsigned short th = f2bf(tv);
        int rr = mt * 16 + quad * 4 + r;
        Ahi[rr * LDSA + col] = th;
        Alo[rr * LDSA + col] = f2bf(tv - bf2f(th));
      }
  }
  __syncthreads();  // B3

  zacc(acc);
#pragma unroll
  for (int ks = 0; ks < 4; ++ks) {
    bs8 ah[4], al[4];
#pragma unroll
    for (int mt = 0; mt < 4; ++mt) {
      ah[mt] = *(const bs8*)(Ahi + (mt * 16 + ln) * LDSA + ks * 32 + quad * 8);
      al[mt] = *(const bs8*)(Alo + (mt * 16 + ln) * LDSA + ks * 32 + quad * 8);
    }
#pragma unroll
    for (int nt = 0; nt < 2; ++nt)
#pragma unroll
      for (int mt = 0; mt < 4; ++mt) {
        acc[mt][nt] = __builtin_amdgcn_mfma_f32_16x16x32_bf16(al[mt], b2h[ks][nt], acc[mt][nt], 0, 0, 0);
        acc[mt][nt] = __builtin_amdgcn_mfma_f32_16x16x32_bf16(ah[mt], b2l[ks][nt], acc[mt][nt], 0, 0, 0);
        acc[mt][nt] = __builtin_amdgcn_mfma_f32_16x16x32_bf16(ah[mt], b2h[ks][nt], acc[mt][nt], 0, 0, 0);
      }
  }
  __syncthreads();  // B4
  float* Tf = (float*)AB;
#pragma unroll
  for (int nt = 0; nt < 2; ++nt) {
    int col = (wq * 2 + nt) * 16 + ln;
    float bb = b2[col];
#pragma unroll
    for (int mt = 0; mt < 4; ++mt)
#pragma unroll
      for (int r = 0; r < 4; ++r) {
        int rl = mt * 16 + quad * 4 + r;
        int gr = row0 + rl;
        Tf[rl * LDSF + col] = (acc[mt][nt][r] + bb) * nmask[gr];
      }
  }
  __syncthreads();  // B5
  if (tid < 128) {
    int col = tid;
    float a2 = 0.f;
    int cur = kk[0];
    for (int r = 0; r < 64; ++r) {
      int k2 = kk[r];
      if (k2 != cur) {
        atomicAdd(&num[((size_t)(cur & 63) * CC + (cur >> 6)) * HH + col], a2);
        a2 = 0.f;
        cur = k2;
      }
      a2 += Tf[r * LDSF + col];
    }
    atomicAdd(&num[((size_t)(cur & 63) * CC + (cur >> 6)) * HH + col], a2);
  }
}

// ---------------- pool finalize ----------------
__global__ __launch_bounds__(256) void pool_finalize_kernel(const float* __restrict__ num,
                                                            const int* __restrict__ batch,
                                                            const float* __restrict__ nmask,
                                                            float* __restrict__ outp) {
  int g = blockIdx.x >> 2, c = blockIdx.x & 3;
  int lo = 0, hi = NN;
  while (lo < hi) { int m = (lo + hi) >> 1; if (batch[m] < g) lo = m + 1; else hi = m; }
  int start = lo;
  hi = NN;
  while (lo < hi) { int m = (lo + hi) >> 1; if (batch[m] < g + 1) lo = m + 1; else hi = m; }
  int end = lo;
  int tid = threadIdx.x;
  float d = 0.f;
  for (int n = start + tid; n < end; n += 256) d += nmask[c * NN + n];
#pragma unroll
  for (int k = 1; k < 64; k <<= 1) d += __shfl_xor(d, k);
  __shared__ float ws4[4];
  if ((tid & 63) == 0) ws4[tid >> 6] = d;
  __syncthreads();
  float den = ws4[0] + ws4[1] + ws4[2] + ws4[3] + 1e-7f;
  if (tid < 128) {
    int idx = blockIdx.x * 128 + tid;
    outp[idx] = num[idx] / den;
  }
}

extern "C" void kernel_launch(void* const* d_in, const int* in_sizes, int n_in,
                              void* d_out, int out_size, void* d_ws, size_t ws_size,
                              hipStream_t stream) {
  const float* x_in  = (const float*)d_in[0];
  const int*   batch = (const int*)d_in[1];
  const int*   eidx  = (const int*)d_in[2];
  const float* eattr = (const float*)d_in[3];
  const float* nmask = (const float*)d_in[4];
  const float* emask = (const float*)d_in[5];
  const float* Wbe   = (const float*)d_in[6];
  const float* bbe   = (const float*)d_in[7];
  const float* epsp  = (const float*)d_in[8];
  const float* W1    = (const float*)d_in[9];
  const float* b1    = (const float*)d_in[10];
  const float* W2    = (const float*)d_in[11];
  const float* b2    = (const float*)d_in[12];
  const float* Wm1   = (const float*)d_in[13];
  const float* bm1   = (const float*)d_in[14];
  const float* Wm2   = (const float*)d_in[15];
  const float* bm2   = (const float*)d_in[16];
  float* outp = (float*)d_out;

  const int* srcp = eidx;
  const int* dstp = eidx + EN;

  char* ws = (char*)d_ws;
  float* ee   = (float*)(ws);                  // 102,400,000 B
  float* hbuf = (float*)(ws + 102400000);
  float* xbuf = (float*)(ws + 204800000);
  int* counts  = (int*)(ws + 307200000);       // 200,000 B
  int* offsets = (int*)(ws + 307400000);       // 200,004 B
  int* cursor  = (int*)(ws + 307600008);       // 200,000 B
  int2* csr_es = (int2*)(ws + 307800016);      // 1,600,000 B (8-aligned)
  float4* emask_s = (float4*)(ws + 309400016); // 3,200,000 B (16-aligned)
  unsigned short* wts = (unsigned short*)(ws + 312600016);  // 12*32768 B
  int* bsums = (int*)ws;                 // overlay: before ee_kernel writes ee
  int* boffs = (int*)(ws + 1024);
  float* num = (float*)ws;               // overlay: after last ee read

  const int NB = (NN + 255) / 256;  // 196

  hipMemsetAsync(counts, 0, NN * sizeof(int), stream);
  count_kernel<<<(EN + 255) / 256, 256, 0, stream>>>(dstp, counts);
  block_sum_kernel<<<NB, 256, 0, stream>>>(counts, bsums);
  bsum_scan_kernel<<<1, 256, 0, stream>>>(bsums, boffs, NB);
  block_scan_kernel<<<NB, 256, 0, stream>>>(counts, boffs, offsets, cursor);
  fill_kernel<<<(EN + 255) / 256, 256, 0, stream>>>(dstp, srcp, emask, cursor, csr_es, emask_s);

  prep_w_kernel<<<384, 256, 0, stream>>>(W1, W2, Wm1, Wm2, wts);

  ee_kernel<<<EN / 16, 256, 0, stream>>>(eattr, Wbe, bbe, ee);

  // layer 0
  agg_kernel<<<NN / 4, 256, 0, stream>>>(x_in, ee, offsets, csr_es, emask_s, epsp, 0, hbuf);
  mlp_kernel<<<HTILE, 256, 0, stream>>>(hbuf, wts + 0, wts + 16384, b1,
                                        wts + 65536, wts + 81920, b2, xbuf);
  // layer 1
  agg_kernel<<<NN / 4, 256, 0, stream>>>(xbuf, ee, offsets, csr_es, emask_s, epsp, 1, hbuf);
  mlp_kernel<<<HTILE, 256, 0, stream>>>(hbuf, wts + 32768, wts + 49152, b1 + 128,
                                        wts + 98304, wts + 114688, b2 + 128, xbuf);
  // final node MLP with fused masked-sum pooling
  hipMemsetAsync(num, 0, 131072, stream);
  mlp_pool_kernel<<<NTILE, 256, 0, stream>>>(xbuf, wts + 131072, wts + 147456, bm1,
                                             wts + 163840, wts + 180224, bm2,
                                             nmask, batch, num);
  pool_finalize_kernel<<<GG * CC, 256, 0, stream>>>(num, batch, nmask, outp);
}

// Round 7
// 678.481 us; speedup vs baseline: 1.2741x; 1.0950x over previous
//
#include <hip/hip_runtime.h>
#include <math.h>

#define NN 50000
#define EN 200000
#define CC 4
#define HH 128
#define GG 64
#define LDSA 136   // padded stride for pool-variant tile
#define LDSF 132   // f32 stride for fused-pool tile

typedef __attribute__((ext_vector_type(8))) short bs8;
typedef __attribute__((ext_vector_type(4))) float f32x4;
typedef __attribute__((ext_vector_type(2))) float f32x2;

__device__ __forceinline__ unsigned short f2bf(float f) {
  unsigned int u = __float_as_uint(f);
  u += 0x7FFFu + ((u >> 16) & 1u);
  return (unsigned short)(u >> 16);
}
__device__ __forceinline__ float bf2f(unsigned short h) {
  return __uint_as_float(((unsigned int)h) << 16);
}
// fast erf-GELU: A&S 7.1.26 minimax (|erf err| ~1.5e-7) + hw rcp/exp
__device__ __forceinline__ float gelu_f(float x) {
  float z = fabsf(x) * 0.7071067811865476f;
  float t = __builtin_amdgcn_rcpf(fmaf(0.3275911f, z, 1.0f));
  float poly = t * fmaf(t, fmaf(t, fmaf(t, fmaf(t, 1.061405429f, -1.453152027f),
                                        1.421413741f), -0.284496736f), 0.254829592f);
  float e = fmaf(-poly, __expf(-z * z), 1.0f);
  return 0.5f * x * (1.0f + copysignf(e, x));
}
// 2*gelu(x) — caller pre-folds the 0.5 into the edge mask
__device__ __forceinline__ float gelu2_f(float x) {
  float z = fabsf(x) * 0.7071067811865476f;
  float t = __builtin_amdgcn_rcpf(fmaf(0.3275911f, z, 1.0f));
  float poly = t * fmaf(t, fmaf(t, fmaf(t, fmaf(t, 1.061405429f, -1.453152027f),
                                        1.421413741f), -0.284496736f), 0.254829592f);
  float e = fmaf(-poly, __expf(-z * z), 1.0f);
  return x * (1.0f + copysignf(e, x));
}

// ---------------- CSR build ----------------
__global__ __launch_bounds__(256) void count_kernel(const int* __restrict__ dst,
                                                    int* __restrict__ counts) {
  int e = blockIdx.x * 256 + threadIdx.x;
  if (e < EN) atomicAdd(&counts[dst[e]], 1);
}

__global__ __launch_bounds__(256) void block_sum_kernel(const int* __restrict__ counts,
                                                        int* __restrict__ bsums) {
  int tid = threadIdx.x;
  int i = blockIdx.x * 256 + tid;
  int v = (i < NN) ? counts[i] : 0;
#pragma unroll
  for (int d = 1; d < 64; d <<= 1) v += __shfl_xor(v, d);
  __shared__ int ws4[4];
  if ((tid & 63) == 0) ws4[tid >> 6] = v;
  __syncthreads();
  if (tid == 0) bsums[blockIdx.x] = ws4[0] + ws4[1] + ws4[2] + ws4[3];
}

__global__ __launch_bounds__(256) void bsum_scan_kernel(const int* __restrict__ bsums,
                                                        int* __restrict__ boffs, int nb) {
  int tid = threadIdx.x, lane = tid & 63, wv = tid >> 6;
  int v = (tid < nb) ? bsums[tid] : 0;
  int s = v;
#pragma unroll
  for (int d = 1; d < 64; d <<= 1) { int t = __shfl_up(s, d); if (lane >= d) s += t; }
  __shared__ int wsum[4];
  if (lane == 63) wsum[wv] = s;
  __syncthreads();
  int pre = 0;
  for (int j = 0; j < wv; ++j) pre += wsum[j];
  if (tid < nb) boffs[tid] = pre + s - v;
}

__global__ __launch_bounds__(256) void block_scan_kernel(const int* __restrict__ counts,
                                                         const int* __restrict__ boffs,
                                                         int* __restrict__ offsets,
                                                         int* __restrict__ cursor) {
  int tid = threadIdx.x, lane = tid & 63, wv = tid >> 6;
  int i = blockIdx.x * 256 + tid;
  int v = (i < NN) ? counts[i] : 0;
  int s = v;
#pragma unroll
  for (int d = 1; d < 64; d <<= 1) { int t = __shfl_up(s, d); if (lane >= d) s += t; }
  __shared__ int wsum[4];
  if (lane == 63) wsum[wv] = s;
  __syncthreads();
  int pre = boffs[blockIdx.x];
  for (int j = 0; j < wv; ++j) pre += wsum[j];
  if (i < NN) { int e = pre + s - v; offsets[i] = e; cursor[i] = e; }
  if (i == 0) offsets[NN] = EN;
}

// fill: CSR-ordered side arrays (kills dependent index chain + emask line waste)
__global__ __launch_bounds__(256) void fill_kernel(const int* __restrict__ dst,
                                                   const int* __restrict__ src,
                                                   const float* __restrict__ emask,
                                                   int* __restrict__ cursor,
                                                   int2* __restrict__ csr_es,
                                                   float4* __restrict__ emask_s) {
  int e = blockIdx.x * 256 + threadIdx.x;
  if (e < EN) {
    int s = src[e];
    float m0 = emask[e];
    float m1 = emask[EN + e];
    float m2 = emask[2 * EN + e];
    float m3 = emask[3 * EN + e];
    int pos = atomicAdd(&cursor[dst[e]], 1);
    csr_es[pos] = make_int2(e, s);
    emask_s[pos] = make_float4(m0, m1, m2, m3);
  }
}

// ---------------- weight prep: transpose + hi/lo bf16 split ----------------------
__global__ __launch_bounds__(256) void prep_w_kernel(const float* __restrict__ W1,
                                                     const float* __restrict__ W2,
                                                     const float* __restrict__ Wm1,
                                                     const float* __restrict__ Wm2,
                                                     unsigned short* __restrict__ wts) {
  int m = blockIdx.x >> 6;
  int idx = (blockIdx.x & 63) * 256 + threadIdx.x;  // 0..16383
  const float* src = (m == 0) ? W1 : (m == 1) ? W1 + 16384 : (m == 2) ? W2
                     : (m == 3) ? W2 + 16384 : (m == 4) ? Wm1 : Wm2;
  unsigned short* dhi = wts + m * 32768;
  unsigned short* dlo = dhi + 16384;
  int n = idx >> 7, k = idx & 127;
  float v = src[k * HH + n];  // src [k][n] -> dst [n][k]
  unsigned short hi = f2bf(v);
  dhi[n * HH + k] = hi;
  dlo[n * HH + k] = f2bf(v - bf2f(hi));
}

// ---------------- bond encoder: 16 edges per block ----------------
__global__ __launch_bounds__(256) void ee_kernel(const float* __restrict__ eattr,
                                                 const float* __restrict__ Wbe,
                                                 const float* __restrict__ bbe,
                                                 float* __restrict__ ee) {
  __shared__ float Ws[16 * HH];
  __shared__ float Ea[16 * 16];
  int tid = threadIdx.x;
  int e0 = blockIdx.x * 16;
#pragma unroll
  for (int i = 0; i < 8; ++i) Ws[tid + i * 256] = Wbe[tid + i * 256];
  Ea[tid] = eattr[(size_t)e0 * 16 + tid];
  __syncthreads();
  int h = tid & 127, half = tid >> 7;
  float bb = bbe[h];
#pragma unroll
  for (int j = 0; j < 8; ++j) {
    int el = j * 2 + half;
    float acc = bb;
#pragma unroll
    for (int d = 0; d < 16; ++d) acc += Ea[el * 16 + d] * Ws[d * HH + h];
    ee[(size_t)(e0 + el) * HH + h] = acc;
  }
}

// ---------------- MLP helpers ----------------------------------------------------
__device__ __forceinline__ void loadW(const unsigned short* __restrict__ whi,
                                      const unsigned short* __restrict__ wlo,
                                      bs8 (&bh)[4][2], bs8 (&bl)[4][2],
                                      int ln, int quad, int wq) {
#pragma unroll
  for (int ks = 0; ks < 4; ++ks)
#pragma unroll
    for (int nt = 0; nt < 2; ++nt) {
      int wrow = ((wq * 2 + nt) * 16 + ln) * HH + ks * 32 + quad * 8;
      bh[ks][nt] = *(const bs8*)(whi + wrow);
      bl[ks][nt] = *(const bs8*)(wlo + wrow);
    }
}
__device__ __forceinline__ void zacc(f32x4 (&acc)[4][2]) {
#pragma unroll
  for (int mt = 0; mt < 4; ++mt)
#pragma unroll
    for (int nt = 0; nt < 2; ++nt)
#pragma unroll
      for (int r = 0; r < 4; ++r) acc[mt][nt][r] = 0.f;
}
// 3-term GEMM over XOR-swizzled 64xHH LDS tile with preloaded W frags
__device__ __forceinline__ void gemm3(const unsigned short* Ahi, const unsigned short* Alo,
                                      const bs8 (&bh)[4][2], const bs8 (&bl)[4][2],
                                      f32x4 (&acc)[4][2], int ln, int quad) {
#pragma unroll
  for (int ks = 0; ks < 4; ++ks) {
    bs8 ah[4], al[4];
    int sb = ((ks * 4 + quad) ^ ln) * 8;
#pragma unroll
    for (int mt = 0; mt < 4; ++mt) {
      ah[mt] = *(const bs8*)(Ahi + (mt * 16 + ln) * HH + sb);
      al[mt] = *(const bs8*)(Alo + (mt * 16 + ln) * HH + sb);
    }
#pragma unroll
    for (int nt = 0; nt < 2; ++nt)
#pragma unroll
      for (int mt = 0; mt < 4; ++mt) {
        acc[mt][nt] = __builtin_amdgcn_mfma_f32_16x16x32_bf16(al[mt], bh[ks][nt], acc[mt][nt], 0, 0, 0);
        acc[mt][nt] = __builtin_amdgcn_mfma_f32_16x16x32_bf16(ah[mt], bl[ks][nt], acc[mt][nt], 0, 0, 0);
        acc[mt][nt] = __builtin_amdgcn_mfma_f32_16x16x32_bf16(ah[mt], bh[ks][nt], acc[mt][nt], 0, 0, 0);
      }
  }
}
// t = gelu(acc+b1) -> swizzled LDS hi/lo
__device__ __forceinline__ void tstage(unsigned short* Ahi, unsigned short* Alo,
                                       const float* __restrict__ b1v, f32x4 (&acc)[4][2],
                                       int ln, int quad, int wq) {
#pragma unroll
  for (int nt = 0; nt < 2; ++nt) {
    int col = (wq * 2 + nt) * 16 + ln;
    int cb = col >> 3, co = col & 7;
    float bb = b1v[col];
#pragma unroll
    for (int mt = 0; mt < 4; ++mt)
#pragma unroll
      for (int r = 0; r < 4; ++r) {
        float tv = gelu_f(acc[mt][nt][r] + bb);
        unsigned short th = f2bf(tv);
        int rr = mt * 16 + quad * 4 + r;
        int sof = rr * HH + (cb ^ (rr & 15)) * 8 + co;
        Ahi[sof] = th;
        Alo[sof] = f2bf(tv - bf2f(th));
      }
  }
}

// ---------------- fused layer: agg (depth-2 pipeline) + MLP on one 64-row tile ---
// Block = 16 nodes x 4 channels. Tile row rr = c*16 + nn (fragment mt <-> channel,
// ln <-> node). Wave wv aggregates nodes n0+4wv..+3, writing h = (1+eps)*x + agg
// straight into the XOR-swizzled bf16 hi/lo LDS tile (no hbuf round-trip; numerics
// identical to the split version: same f32 h hi/lo-split). Then the proven
// GEMM1 -> t -> GEMM2 chain runs unchanged; epilogue writes out[(c*NN+n)*HH+col].
__global__ __launch_bounds__(256, 4) void layer_kernel(
    const float* __restrict__ x,
    const float* __restrict__ ee,
    const int* __restrict__ off,
    const int2* __restrict__ csr_es,
    const float4* __restrict__ emask_s,
    const float* __restrict__ epsp, int layer,
    const unsigned short* __restrict__ w1hi, const unsigned short* __restrict__ w1lo,
    const float* __restrict__ b1,
    const unsigned short* __restrict__ w2hi, const unsigned short* __restrict__ w2lo,
    const float* __restrict__ b2,
    float* __restrict__ out) {
  __shared__ __align__(16) unsigned short AB[2 * 64 * HH];  // 32 KB
  unsigned short* Ahi = AB;
  unsigned short* Alo = AB + 64 * HH;
  int tid = threadIdx.x;
  int lane = tid & 63, wq = tid >> 6;
  int ln = lane & 15, quad = lane >> 4;
  int n0 = blockIdx.x * 16;
  int c2 = lane * 2;
  float ep = 1.0f + epsp[layer];
  int blk = lane >> 2;        // 16B-block index of this lane's col pair
  int wo = (lane & 3) * 2;    // within-block element offset

  // ---- agg phase: 4 nodes per wave, R3-proven depth-2 pipeline per node ----
  for (int j = 0; j < 4; ++j) {
    int nn = wq * 4 + j;
    int v = n0 + nn;
    float2 acc[CC];
#pragma unroll
    for (int c = 0; c < CC; ++c) { acc[c].x = 0.f; acc[c].y = 0.f; }
    int beg = off[v], end = off[v + 1];

    float2 eeC; float2 xC[CC]; float emC[CC];
    int2 esN = make_int2(0, 0);
    eeC.x = 0.f; eeC.y = 0.f;
#pragma unroll
    for (int c = 0; c < CC; ++c) { xC[c].x = 0.f; xC[c].y = 0.f; emC[c] = 0.f; }

    if (beg < end) {
      int2 es0 = csr_es[beg];
      eeC = *(const float2*)(ee + (size_t)es0.x * HH + c2);
#pragma unroll
      for (int c = 0; c < CC; ++c)
        xC[c] = *(const float2*)(x + ((size_t)c * NN + es0.y) * HH + c2);
      float4 m = emask_s[beg];
      emC[0] = 0.5f * m.x; emC[1] = 0.5f * m.y; emC[2] = 0.5f * m.z; emC[3] = 0.5f * m.w;
      if (beg + 1 < end) esN = csr_es[beg + 1];
    }

    for (int t = beg; t < end; ++t) {
      float2 eeB; float2 xB[CC]; float emB[CC];
      int2 esNN = make_int2(0, 0);
      if (t + 1 < end) {
        eeB = *(const float2*)(ee + (size_t)esN.x * HH + c2);
#pragma unroll
        for (int c = 0; c < CC; ++c)
          xB[c] = *(const float2*)(x + ((size_t)c * NN + esN.y) * HH + c2);
        float4 m = emask_s[t + 1];
        emB[0] = 0.5f * m.x; emB[1] = 0.5f * m.y; emB[2] = 0.5f * m.z; emB[3] = 0.5f * m.w;
        if (t + 2 < end) esNN = csr_es[t + 2];
      } else {
        eeB.x = 0.f; eeB.y = 0.f;
#pragma unroll
        for (int c = 0; c < CC; ++c) { xB[c].x = 0.f; xB[c].y = 0.f; emB[c] = 0.f; }
      }
#pragma unroll
      for (int c = 0; c < CC; ++c) {
        acc[c].x += gelu2_f(xC[c].x + eeC.x) * emC[c];
        acc[c].y += gelu2_f(xC[c].y + eeC.y) * emC[c];
      }
      eeC = eeB;
#pragma unroll
      for (int c = 0; c < CC; ++c) { xC[c] = xB[c]; emC[c] = emB[c]; }
      esN = esNN;
    }

    // h = (1+eps)*x_self + acc -> bf16 hi/lo into swizzled tile row rr = c*16+nn
#pragma unroll
    for (int c = 0; c < CC; ++c) {
      float2 xs = *(const float2*)(x + ((size_t)c * NN + v) * HH + c2);
      float o0 = fmaf(ep, xs.x, acc[c].x);
      float o1 = fmaf(ep, xs.y, acc[c].y);
      int rr = c * 16 + nn;
      int base = rr * HH + ((blk ^ (rr & 15)) * 8) + wo;
      unsigned short h0 = f2bf(o0), h1 = f2bf(o1);
      ushort2 hv; hv.x = h0; hv.y = h1;
      ushort2 lv; lv.x = f2bf(o0 - bf2f(h0)); lv.y = f2bf(o1 - bf2f(h1));
      *(ushort2*)(Ahi + base) = hv;
      *(ushort2*)(Alo + base) = lv;
    }
  }

  // W1 fragment loads issue here; latency overlaps the barrier wait
  bs8 w1h[4][2], w1l[4][2];
  loadW(w1hi, w1lo, w1h, w1l, ln, quad, wq);
  __syncthreads();  // A tile staged

  f32x4 acc[4][2];
  zacc(acc);
  gemm3(Ahi, Alo, w1h, w1l, acc, ln, quad);
  __syncthreads();  // GEMM1 LDS reads done

  bs8 w2h[4][2], w2l[4][2];
  loadW(w2hi, w2lo, w2h, w2l, ln, quad, wq);
  tstage(Ahi, Alo, b1, acc, ln, quad, wq);
  __syncthreads();  // t staged

  zacc(acc);
  gemm3(Ahi, Alo, w2h, w2l, acc, ln, quad);

  // epilogue: outer gelu, row rl = mt*16 + quad*4 + r -> (c=mt, n=n0+quad*4+r)
#pragma unroll
  for (int nt = 0; nt < 2; ++nt) {
    int col = (wq * 2 + nt) * 16 + ln;
    float bb = b2[col];
#pragma unroll
    for (int mt = 0; mt < 4; ++mt)
#pragma unroll
      for (int r = 0; r < 4; ++r) {
        float o = gelu_f(acc[mt][nt][r] + bb);
        out[((size_t)mt * NN + n0 + quad * 4 + r) * HH + col] = o;
      }
  }
}

// ---------------- final MLP + fused masked-sum pooling (R3 proven form) ----------
__global__ __launch_bounds__(256, 2) void mlp_pool_kernel(
    const float* __restrict__ in,
    const unsigned short* __restrict__ w1hi, const unsigned short* __restrict__ w1lo,
    const float* __restrict__ b1,
    const unsigned short* __restrict__ w2hi, const unsigned short* __restrict__ w2lo,
    const float* __restrict__ b2,
    const float* __restrict__ nmask, const int* __restrict__ batch,
    float* __restrict__ num) {
  __shared__ __align__(16) unsigned short AB[128 * LDSA];
  __shared__ int kk[64];
  unsigned short* Ahi = AB;
  unsigned short* Alo = AB + 64 * LDSA;
  int tid = threadIdx.x;
  int row0 = blockIdx.x * 64;
  int lane = tid & 63, wq = tid >> 6;
  int ln = lane & 15, quad = lane >> 4;

  bs8 b1h[4][2], b1l[4][2];
  loadW(w1hi, w1lo, b1h, b1l, ln, quad, wq);
#pragma unroll
  for (int i = 0; i < 8; ++i) {
    int idx = tid + i * 256;
    int r = idx >> 5, cc4 = idx & 31;
    f32x4 vv = __builtin_nontemporal_load(
        (const f32x4*)(in + (size_t)(row0 + r) * HH + cc4 * 4));
    unsigned short h0 = f2bf(vv[0]), h1 = f2bf(vv[1]), h2 = f2bf(vv[2]), h3 = f2bf(vv[3]);
    ushort4 hv; hv.x = h0; hv.y = h1; hv.z = h2; hv.w = h3;
    ushort4 lv;
    lv.x = f2bf(vv[0] - bf2f(h0)); lv.y = f2bf(vv[1] - bf2f(h1));
    lv.z = f2bf(vv[2] - bf2f(h2)); lv.w = f2bf(vv[3] - bf2f(h3));
    *(ushort4*)(Ahi + r * LDSA + cc4 * 4) = hv;
    *(ushort4*)(Alo + r * LDSA + cc4 * 4) = lv;
  }
  if (tid < 64) {
    int gr = row0 + tid;
    int c = gr / NN;
    int n = gr - c * NN;
    kk[tid] = (c << 6) | batch[n];
  }
  __syncthreads();  // B1

  f32x4 acc[4][2];
  zacc(acc);
#pragma unroll
  for (int ks = 0; ks < 4; ++ks) {
    bs8 ah[4], al[4];
#pragma unroll
    for (int mt = 0; mt < 4; ++mt) {
      ah[mt] = *(const bs8*)(Ahi + (mt * 16 + ln) * LDSA + ks * 32 + quad * 8);
      al[mt] = *(const bs8*)(Alo + (mt * 16 + ln) * LDSA + ks * 32 + quad * 8);
    }
#pragma unroll
    for (int nt = 0; nt < 2; ++nt)
#pragma unroll
      for (int mt = 0; mt < 4; ++mt) {
        acc[mt][nt] = __builtin_amdgcn_mfma_f32_16x16x32_bf16(al[mt], b1h[ks][nt], acc[mt][nt], 0, 0, 0);
        acc[mt][nt] = __builtin_amdgcn_mfma_f32_16x16x32_bf16(ah[mt], b1l[ks][nt], acc[mt][nt], 0, 0, 0);
        acc[mt][nt] = __builtin_amdgcn_mfma_f32_16x16x32_bf16(ah[mt], b1h[ks][nt], acc[mt][nt], 0, 0, 0);
      }
  }
  __syncthreads();  // B2

  bs8 b2h[4][2], b2l[4][2];
  loadW(w2hi, w2lo, b2h, b2l, ln, quad, wq);
#pragma unroll
  for (int nt = 0; nt < 2; ++nt) {
    int col = (wq * 2 + nt) * 16 + ln;
    float bb = b1[col];
#pragma unroll
    for (int mt = 0; mt < 4; ++mt)
#pragma unroll
      for (int r = 0; r < 4; ++r) {
        float tv = gelu_f(acc[mt][nt][r] + bb);
        unsigned short th = f2bf(tv);
        int rr = mt * 16 + quad * 4 + r;
        Ahi[rr * LDSA + col] = th;
        Alo[rr * LDSA + col] = f2bf(tv - bf2f(th));
      }
  }
  __syncthreads();  // B3

  zacc(acc);
#pragma unroll
  for (int ks = 0; ks < 4; ++ks) {
    bs8 ah[4], al[4];
#pragma unroll
    for (int mt = 0; mt < 4; ++mt) {
      ah[mt] = *(const bs8*)(Ahi + (mt * 16 + ln) * LDSA + ks * 32 + quad * 8);
      al[mt] = *(const bs8*)(Alo + (mt * 16 + ln) * LDSA + ks * 32 + quad * 8);
    }
#pragma unroll
    for (int nt = 0; nt < 2; ++nt)
#pragma unroll
      for (int mt = 0; mt < 4; ++mt) {
        acc[mt][nt] = __builtin_amdgcn_mfma_f32_16x16x32_bf16(al[mt], b2h[ks][nt], acc[mt][nt], 0, 0, 0);
        acc[mt][nt] = __builtin_amdgcn_mfma_f32_16x16x32_bf16(ah[mt], b2l[ks][nt], acc[mt][nt], 0, 0, 0);
        acc[mt][nt] = __builtin_amdgcn_mfma_f32_16x16x32_bf16(ah[mt], b2h[ks][nt], acc[mt][nt], 0, 0, 0);
      }
  }
  __syncthreads();  // B4
  float* Tf = (float*)AB;
#pragma unroll
  for (int nt = 0; nt < 2; ++nt) {
    int col = (wq * 2 + nt) * 16 + ln;
    float bb = b2[col];
#pragma unroll
    for (int mt = 0; mt < 4; ++mt)
#pragma unroll
      for (int r = 0; r < 4; ++r) {
        int rl = mt * 16 + quad * 4 + r;
        int gr = row0 + rl;
        Tf[rl * LDSF + col] = (acc[mt][nt][r] + bb) * nmask[gr];
      }
  }
  __syncthreads();  // B5
  if (tid < 128) {
    int col = tid;
    float a2 = 0.f;
    int cur = kk[0];
    for (int r = 0; r < 64; ++r) {
      int k2 = kk[r];
      if (k2 != cur) {
        atomicAdd(&num[((size_t)(cur & 63) * CC + (cur >> 6)) * HH + col], a2);
        a2 = 0.f;
        cur = k2;
      }
      a2 += Tf[r * LDSF + col];
    }
    atomicAdd(&num[((size_t)(cur & 63) * CC + (cur >> 6)) * HH + col], a2);
  }
}

// ---------------- pool finalize ----------------
__global__ __launch_bounds__(256) void pool_finalize_kernel(const float* __restrict__ num,
                                                            const int* __restrict__ batch,
                                                            const float* __restrict__ nmask,
                                                            float* __restrict__ outp) {
  int g = blockIdx.x >> 2, c = blockIdx.x & 3;
  int lo = 0, hi = NN;
  while (lo < hi) { int m = (lo + hi) >> 1; if (batch[m] < g) lo = m + 1; else hi = m; }
  int start = lo;
  hi = NN;
  while (lo < hi) { int m = (lo + hi) >> 1; if (batch[m] < g + 1) lo = m + 1; else hi = m; }
  int end = lo;
  int tid = threadIdx.x;
  float d = 0.f;
  for (int n = start + tid; n < end; n += 256) d += nmask[c * NN + n];
#pragma unroll
  for (int k = 1; k < 64; k <<= 1) d += __shfl_xor(d, k);
  __shared__ float ws4[4];
  if ((tid & 63) == 0) ws4[tid >> 6] = d;
  __syncthreads();
  float den = ws4[0] + ws4[1] + ws4[2] + ws4[3] + 1e-7f;
  if (tid < 128) {
    int idx = blockIdx.x * 128 + tid;
    outp[idx] = num[idx] / den;
  }
}

extern "C" void kernel_launch(void* const* d_in, const int* in_sizes, int n_in,
                              void* d_out, int out_size, void* d_ws, size_t ws_size,
                              hipStream_t stream) {
  const float* x_in  = (const float*)d_in[0];
  const int*   batch = (const int*)d_in[1];
  const int*   eidx  = (const int*)d_in[2];
  const float* eattr = (const float*)d_in[3];
  const float* nmask = (const float*)d_in[4];
  const float* emask = (const float*)d_in[5];
  const float* Wbe   = (const float*)d_in[6];
  const float* bbe   = (const float*)d_in[7];
  const float* epsp  = (const float*)d_in[8];
  const float* W1    = (const float*)d_in[9];
  const float* b1    = (const float*)d_in[10];
  const float* W2    = (const float*)d_in[11];
  const float* b2    = (const float*)d_in[12];
  const float* Wm1   = (const float*)d_in[13];
  const float* bm1   = (const float*)d_in[14];
  const float* Wm2   = (const float*)d_in[15];
  const float* bm2   = (const float*)d_in[16];
  float* outp = (float*)d_out;

  const int* srcp = eidx;
  const int* dstp = eidx + EN;

  char* ws = (char*)d_ws;
  float* ee   = (float*)(ws);                  // 102,400,000 B
  float* hbuf = (float*)(ws + 102400000);      // layer-0 output
  float* xbuf = (float*)(ws + 204800000);      // layer-1 output
  int* counts  = (int*)(ws + 307200000);       // 200,000 B
  int* offsets = (int*)(ws + 307400000);       // 200,004 B
  int* cursor  = (int*)(ws + 307600008);       // 200,000 B
  int2* csr_es = (int2*)(ws + 307800016);      // 1,600,000 B (8-aligned)
  float4* emask_s = (float4*)(ws + 309400016); // 3,200,000 B (16-aligned)
  unsigned short* wts = (unsigned short*)(ws + 312600016);  // 12*32768 B
  int* bsums = (int*)ws;                 // overlay: before ee_kernel writes ee
  int* boffs = (int*)(ws + 1024);
  float* num = (float*)ws;               // overlay: after last ee read

  const int NB = (NN + 255) / 256;  // 196

  hipMemsetAsync(counts, 0, NN * sizeof(int), stream);
  count_kernel<<<(EN + 255) / 256, 256, 0, stream>>>(dstp, counts);
  block_sum_kernel<<<NB, 256, 0, stream>>>(counts, bsums);
  bsum_scan_kernel<<<1, 256, 0, stream>>>(bsums, boffs, NB);
  block_scan_kernel<<<NB, 256, 0, stream>>>(counts, boffs, offsets, cursor);
  fill_kernel<<<(EN + 255) / 256, 256, 0, stream>>>(dstp, srcp, emask, cursor, csr_es, emask_s);

  prep_w_kernel<<<384, 256, 0, stream>>>(W1, W2, Wm1, Wm2, wts);

  ee_kernel<<<EN / 16, 256, 0, stream>>>(eattr, Wbe, bbe, ee);

  // layer 0 (fused agg+MLP): x_in -> hbuf
  layer_kernel<<<NN / 16, 256, 0, stream>>>(x_in, ee, offsets, csr_es, emask_s, epsp, 0,
                                            wts + 0, wts + 16384, b1,
                                            wts + 65536, wts + 81920, b2, hbuf);
  // layer 1 (fused agg+MLP): hbuf -> xbuf
  layer_kernel<<<NN / 16, 256, 0, stream>>>(hbuf, ee, offsets, csr_es, emask_s, epsp, 1,
                                            wts + 32768, wts + 49152, b1 + 128,
                                            wts + 98304, wts + 114688, b2 + 128, xbuf);
  // final node MLP with fused masked-sum pooling
  hipMemsetAsync(num, 0, 131072, stream);
  mlp_pool_kernel<<<(CC * NN) / 64, 256, 0, stream>>>(xbuf, wts + 131072, wts + 147456, bm1,
                                                      wts + 163840, wts + 180224, bm2,
                                                      nmask, batch, num);
  pool_finalize_kernel<<<GG * CC, 256, 0, stream>>>(num, batch, nmask, outp);
}